// Round 10
// baseline (203.817 us; speedup 1.0000x reference)
//
#include <hip/hip_runtime.h>

// VectorQuantizerEMA: ze (32,64,2048) f32, codebook (1024,64) f32
#define B_   32
#define D_   64
#define TP_  2048
#define K_   1024
#define N_   (B_ * TP_)          // 65536 rows
#define BETA_ 0.25f

// ws layout (float units):
//   [0,1024)        : nc2[k] = np-replicated f32 ||c_k||^2 (pairwise-8 sum)
//   [1024]          : commit-loss accumulator (float, atomic)
//   [1025]          : ambiguous-row count (unsigned, atomic)
//   [1088,2112)     : histogram (unsigned, atomic)
//   [2112,18496)    : ambiguous list, u32 entries: (row<<10)|guess
//   [18496,84032)   : pre-swizzled bf16 split-table image, 32 tiles x 8KB.
//                     tile t = codes [t*32,t*32+32); per tile: 2048 ushorts hi,
//                     2048 lo; element (r=code&31, dim j) at ushort
//                     idx r*64 + (j ^ ((r&7)<<3))  [16B-chunk XOR swizzle]
#define WS_SC2   0
#define WS_LOSS  1024
#define WS_CNT   1025
#define WS_HIST  1088
#define WS_LIST  2112
#define WS_TBL   18496
#define CAP_     16384

#define MARGIN_  4e-4f

typedef __attribute__((ext_vector_type(8))) short short8v;   // 8 bf16
typedef __attribute__((ext_vector_type(4))) float float4v;   // C/D frag
#define AS1 __attribute__((address_space(1)))
#define AS3 __attribute__((address_space(3)))

static __device__ __forceinline__ unsigned bf16h(float f) {
    unsigned u = __float_as_uint(f);
    return (u + 0x7FFFu + ((u >> 16) & 1u)) >> 16;   // RNE to bf16
}

// ---------------- init: np ||c||^2, swizzled split tables, zero state --------
// 16B vectorized table stores (was 128 x 2B scatter).
__global__ void vq_init(const float* __restrict__ cb, float* __restrict__ ws) {
    int k = blockIdx.x * blockDim.x + threadIdx.x;
    if (k < K_) {
        const float4* c4 = reinterpret_cast<const float4*>(cb + (size_t)k * D_);
        unsigned short* img  = reinterpret_cast<unsigned short*>(ws + WS_TBL);
        unsigned short* tile = img + (size_t)(k >> 5) * 4096;
        const int rr = k & 31;
        float r[8];
#pragma unroll
        for (int i = 0; i < 8; ++i) {
            float4 a = c4[2 * i], b = c4[2 * i + 1];
            float v[8] = {a.x, a.y, a.z, a.w, b.x, b.y, b.z, b.w};
            short8v hi, lo;
#pragma unroll
            for (int j = 0; j < 8; ++j) {
                unsigned hu = bf16h(v[j]);
                float hf = __uint_as_float(hu << 16);
                hi[j] = (short)hu;
                lo[j] = (short)bf16h(v[j] - hf);
                if (i == 0) r[j] = v[j] * v[j]; else r[j] += v[j] * v[j];
            }
            const int off = rr * 64 + ((8 * i) ^ ((rr & 7) << 3));
            *reinterpret_cast<short8v*>(&tile[off])        = hi;
            *reinterpret_cast<short8v*>(&tile[2048 + off]) = lo;
        }
        ws[WS_SC2 + k] = ((r[0] + r[1]) + (r[2] + r[3])) + ((r[4] + r[5]) + (r[6] + r[7]));
        reinterpret_cast<unsigned*>(ws + WS_HIST)[k] = 0u;
        if (k == 0) {
            ws[WS_LOSS] = 0.f;
            reinterpret_cast<unsigned*>(ws)[WS_CNT] = 0u;
        }
    }
}

// ---------------- main: counted-vmcnt ring-pipelined MFMA GEMM ---------------
// R9: per-tile __syncthreads drained vmcnt(0) -> every tile exposed full L2
// stage latency (MfmaUtil 9.5%, 60% stall). Now: 4-buffer ring, depth-3
// prefetch, raw s_barrier + s_waitcnt vmcnt(4) (never 0 mid-loop). Loop vmem
// = stage loads only (sc2 moved to LDS) so the FIFO count is exact:
// at iter tt outstanding = stages tt..tt+2 (6) -> vmcnt(4) retires tile tt.
// STAGE(tt+3) is issued AFTER the barrier (its buffer's readers are done).
__global__ __attribute__((amdgpu_flat_work_group_size(256, 256),
                          amdgpu_waves_per_eu(4, 4)))
void vq_main(const float* __restrict__ ze,
             const float* __restrict__ cb,
             float* __restrict__ out,
             float* __restrict__ ws) {
    __shared__ unsigned short lds[4][4096] __attribute__((aligned(16)));
    __shared__ float sc2_l[K_];
    __shared__ int bidx_sh[64];
    const int tid  = threadIdx.x;
    const int lane = tid & 63;
    const int w    = tid >> 6;
    const int kg   = lane >> 4;        // k-group 0..3
    const int rc   = lane & 15;        // A-row / B-col selector
    const int n0w  = blockIdx.x * 64 + w * 16;   // wave's first row

    // ---- A fragments: x[row=rc][k=s*32+kg*8+e], split to bf16 hi/lo ----
    const int nA = n0w + rc;
    const int bA = nA >> 11, tA = nA & (TP_ - 1);
    const float* zeA = ze + (size_t)bA * (D_ * TP_) + tA;
    short8v ah[2], al[2];
#pragma unroll
    for (int s = 0; s < 2; ++s) {
#pragma unroll
        for (int e = 0; e < 8; ++e) {
            float xv = zeA[(size_t)(s * 32 + kg * 8 + e) * TP_];
            unsigned hu = bf16h(xv);
            float hf = __uint_as_float(hu << 16);
            ah[s][e] = (short)hu;
            al[s][e] = (short)bf16h(xv - hf);
        }
    }

    // stage sc2 (4KB) into LDS: wave-uniform dest + lane*16B
    {
        const float* g = ws + WS_SC2 + w * 256 + lane * 4;
        __builtin_amdgcn_global_load_lds((const AS1 unsigned int*)g,
                                         (AS3 unsigned int*)&sc2_l[w * 256], 16, 0, 0);
    }
    const unsigned short* img = reinterpret_cast<const unsigned short*>(ws + WS_TBL);

    float best[4]  = {3.4e38f, 3.4e38f, 3.4e38f, 3.4e38f};
    float best2[4] = {3.4e38f, 3.4e38f, 3.4e38f, 3.4e38f};
    int   bidx[4]  = {0, 0, 0, 0};

#define STAGE(tt) do {                                                            \
        const unsigned short* _g = img + (size_t)(tt) * 4096 + (size_t)tid * 8;   \
        unsigned short* _l = &lds[(tt) & 3][w * 512];                             \
        __builtin_amdgcn_global_load_lds((const AS1 unsigned int*)_g,             \
                                         (AS3 unsigned int*)_l, 16, 0, 0);        \
        __builtin_amdgcn_global_load_lds((const AS1 unsigned int*)(_g + 2048),    \
                                         (AS3 unsigned int*)(_l + 2048), 16, 0, 0); \
    } while (0)

#define SUBTILE(tt, sub) do {                                                     \
        const int r_  = (sub) * 16 + rc;                                          \
        const int cx0 = (kg * 8) ^ ((r_ & 7) << 3);                               \
        const int cx1 = (32 + kg * 8) ^ ((r_ & 7) << 3);                          \
        const unsigned short* bp = &lds[(tt) & 3][r_ * 64];                       \
        short8v bh0 = *reinterpret_cast<const short8v*>(bp + cx0);                \
        short8v bh1 = *reinterpret_cast<const short8v*>(bp + cx1);                \
        short8v bl0 = *reinterpret_cast<const short8v*>(bp + 2048 + cx0);         \
        short8v bl1 = *reinterpret_cast<const short8v*>(bp + 2048 + cx1);         \
        float4v acc = {0.f, 0.f, 0.f, 0.f};                                       \
        acc = __builtin_amdgcn_mfma_f32_16x16x32_bf16(ah[0], bh0, acc, 0, 0, 0);  \
        acc = __builtin_amdgcn_mfma_f32_16x16x32_bf16(ah[1], bh1, acc, 0, 0, 0);  \
        acc = __builtin_amdgcn_mfma_f32_16x16x32_bf16(ah[0], bl0, acc, 0, 0, 0);  \
        acc = __builtin_amdgcn_mfma_f32_16x16x32_bf16(ah[1], bl1, acc, 0, 0, 0);  \
        acc = __builtin_amdgcn_mfma_f32_16x16x32_bf16(al[0], bh0, acc, 0, 0, 0);  \
        acc = __builtin_amdgcn_mfma_f32_16x16x32_bf16(al[1], bh1, acc, 0, 0, 0);  \
        const int code = (tt) * 32 + (sub) * 16 + rc;                             \
        const float s2 = sc2_l[code];                                             \
        _Pragma("unroll")                                                         \
        for (int r = 0; r < 4; ++r) {                                             \
            float v = fmaf(-2.f, acc[r], s2);                                     \
            if (v < best[r]) { best2[r] = best[r]; best[r] = v; bidx[r] = code; } \
            else if (v < best2[r]) best2[r] = v;                                  \
        }                                                                         \
    } while (0)

    // clean vmcnt baseline: drains A-loads + sc2 stage; publishes sc2_l
    __syncthreads();

    STAGE(0); STAGE(1); STAGE(2);                 // depth-3 prologue (6 instrs)
    for (int tt = 0; tt < 30; ++tt) {
        asm volatile("s_waitcnt vmcnt(4)" ::: "memory");   // tile tt retired
        __builtin_amdgcn_sched_barrier(0);
        __builtin_amdgcn_s_barrier();             // all waves' tile-tt done
        if (tt < 29) STAGE(tt + 3);               // overwrites buf of tile tt-1
        SUBTILE(tt, 0);
        SUBTILE(tt, 1);
    }
    asm volatile("s_waitcnt vmcnt(2)" ::: "memory");
    __builtin_amdgcn_sched_barrier(0);
    __builtin_amdgcn_s_barrier();
    SUBTILE(30, 0); SUBTILE(30, 1);
    asm volatile("s_waitcnt vmcnt(0)" ::: "memory");
    __builtin_amdgcn_sched_barrier(0);
    __builtin_amdgcn_s_barrier();
    SUBTILE(31, 0); SUBTILE(31, 1);
#undef STAGE
#undef SUBTILE

    // reduce (best,best2,idx) across the 16 cols (low 4 lane bits)
#pragma unroll
    for (int r = 0; r < 4; ++r) {
        unsigned fu = __float_as_uint(best[r]);
        fu = (fu & 0x80000000u) ? ~fu : (fu | 0x80000000u);   // order-preserving
        unsigned long long pk = ((unsigned long long)fu << 32) | (unsigned)bidx[r];
        float bf = best[r], b2 = best2[r];
#pragma unroll
        for (int m = 1; m <= 8; m <<= 1) {
            unsigned long long po = __shfl_xor(pk, m, 64);
            float bo  = __shfl_xor(bf, m, 64);
            float b2o = __shfl_xor(b2, m, 64);
            b2 = fminf(fminf(b2, b2o), fmaxf(bf, bo));
            bf = fminf(bf, bo);
            if (po < pk) pk = po;
        }
        best[r] = bf; best2[r] = b2; bidx[r] = (int)(pk & 0x3FFull);
    }

    if (rc == 0) {
        unsigned* gh = reinterpret_cast<unsigned*>(ws + WS_HIST);
#pragma unroll
        for (int r = 0; r < 4; ++r) {
            const int row = kg * 4 + r;
            const int n   = n0w + row;
            const int k   = bidx[r];
            out[(size_t)N_ * D_ + n] = (float)k;
            atomicAdd(&gh[k], 1u);
            if (best2[r] - best[r] < MARGIN_) {
                unsigned slot = atomicAdd(reinterpret_cast<unsigned*>(ws) + WS_CNT, 1u);
                if (slot < CAP_)
                    reinterpret_cast<unsigned*>(ws + WS_LIST)[slot] =
                        ((unsigned)n << 10) | (unsigned)k;
            }
            bidx_sh[w * 16 + row] = k;
        }
    }
    __syncthreads();

    // ---- phase2: zq gather-write + commit loss (coalesced over rows) ----
    const int row  = tid & 63;
    const int half = tid >> 6;
    const int n2 = blockIdx.x * 64 + row;
    const int b2i = n2 >> 11, t2 = n2 & (TP_ - 1);
    const int k2 = bidx_sh[row];
    const float* zer = ze + (size_t)b2i * (D_ * TP_) + t2;
    float* outr = out + (size_t)b2i * (D_ * TP_) + t2;
    const float4* cr4 = reinterpret_cast<const float4*>(cb + (size_t)k2 * D_ + half * 16);
    float lsum = 0.f;
#pragma unroll
    for (int q4 = 0; q4 < 4; ++q4) {
        float4 q = cr4[q4];
        float qv[4] = {q.x, q.y, q.z, q.w};
#pragma unroll
        for (int c = 0; c < 4; ++c) {
            const int d = half * 16 + q4 * 4 + c;
            outr[(size_t)d * TP_] = qv[c];        // ze + (zq - ze) == zq
            float diff = zer[(size_t)d * TP_] - qv[c];
            lsum = fmaf(diff, diff, lsum);
        }
    }
#pragma unroll
    for (int m = 32; m >= 1; m >>= 1) lsum += __shfl_xor(lsum, m, 64);
    if (lane == 0) atomicAdd(ws + WS_LOSS, lsum);
}

// ---------------- fixup: replicate ref grid argmin for ambiguous rows -------
// R9: xr[64] in registers kept spilling under the allocator's occupancy
// heuristic (bench math: ~70us). Now the row lives in LDS, read via a
// volatile pointer (blocks LICM from re-promoting 64 values to registers):
// register footprint ~40 regardless of allocator budget.
__global__ __attribute__((amdgpu_flat_work_group_size(256, 256)))
void vq_fix(const float* __restrict__ ze,
            const float* __restrict__ cb,
            float* __restrict__ out,
            float* __restrict__ ws) {
    __shared__ float xls[4][64];
    const int lane = threadIdx.x & 63;
    const int wl   = threadIdx.x >> 6;
    const unsigned w = blockIdx.x * 4 + wl;                  // wave id, 256 total
    unsigned cnt = reinterpret_cast<const unsigned*>(ws)[WS_CNT];
    if (cnt > CAP_) cnt = CAP_;
    const unsigned* list = reinterpret_cast<const unsigned*>(ws + WS_LIST);
    const float* sc2 = ws + WS_SC2;
    unsigned* gh = reinterpret_cast<unsigned*>(ws + WS_HIST);

    for (unsigned i = w; i < cnt; i += 256) {
        unsigned e = list[i];
        const int n     = (int)(e >> 10);
        const int guess = (int)(e & 1023u);
        const int b  = n >> 11;
        const int tp = n & (TP_ - 1);
        const float* zp = ze + (size_t)b * D_ * TP_ + tp;    // wave-uniform

        xls[wl][lane] = zp[(size_t)lane * TP_];
        asm volatile("s_waitcnt lgkmcnt(0)" ::: "memory");   // ds_write visible

        volatile const float* xw = xls[wl];

        // np pairwise-8 ||x||^2 (bit-exact np.sum(x*x, axis=1))
        float r[8];
#pragma unroll
        for (int j = 0; j < 8; ++j) { float v = xw[j]; r[j] = v * v; }
#pragma unroll
        for (int ii = 1; ii < 8; ++ii)
#pragma unroll
            for (int j = 0; j < 8; ++j) { float v = xw[8 * ii + j]; r[j] += v * v; }
        float nx2 = ((r[0] + r[1]) + (r[2] + r[3])) + ((r[4] + r[5]) + (r[6] + r[7]));

        // 16 codes per lane: dist = fl(fl(nx2+nc2) - 2*fl64->32(dot))
        unsigned long long m = ~0ull;
        const int kbase = lane * 16;
#pragma unroll 1
        for (int kk = 0; kk < 16; ++kk) {
            const int k = kbase + kk;
            const float* cp = cb + (size_t)k * D_;
            double acc = 0.0;
#pragma unroll
            for (int j = 0; j < D_; ++j)
                acc = fma((double)xw[j], (double)cp[j], acc);
            float dotf = (float)acc;
            float A    = nx2 + sc2[k];
            float dist = A - 2.0f * dotf;
            unsigned long long pk =
                ((unsigned long long)__float_as_uint(dist) << 32) | (unsigned)k;
            if (pk < m) m = pk;
        }
#pragma unroll
        for (int s = 32; s >= 1; s >>= 1) {
            unsigned long long o = __shfl_xor(m, s, 64);
            if (o < m) m = o;
        }
        const int gk = (int)(m & 0xFFFFFFFFull);

        if (gk != guess) {
            out[(size_t)b * D_ * TP_ + (size_t)lane * TP_ + tp] = cb[(size_t)gk * D_ + lane];
            float xl = xw[lane];
            float dn = xl - cb[(size_t)gk * D_ + lane];
            float dq = xl - cb[(size_t)guess * D_ + lane];
            float t  = dn * dn - dq * dq;
#pragma unroll
            for (int s = 32; s >= 1; s >>= 1) t += __shfl_xor(t, s, 64);
            if (lane == 0) {
                atomicAdd(ws + WS_LOSS, t);
                out[(size_t)N_ * D_ + n] = (float)gk;
                atomicSub(&gh[guess], 1u);
                atomicAdd(&gh[gk], 1u);
            }
        }
    }
}

// ---------------- finalize: scalars ----------------
__global__ void vq_fin(const float* __restrict__ ws, float* __restrict__ out) {
    __shared__ double red[K_];
    const int t = threadIdx.x;
    const unsigned* gh = reinterpret_cast<const unsigned*>(ws + WS_HIST);
    double p = (double)gh[t] * (1.0 / (double)N_);
    red[t] = -p * log(p + 1e-10);
    __syncthreads();
    for (int s = 512; s > 0; s >>= 1) {
        if (t < s) red[t] += red[t + s];
        __syncthreads();
    }
    if (t == 0) {
        out[(size_t)N_ * D_ + N_]     = BETA_ * ws[WS_LOSS] * (1.0f / (float)(N_ * D_));
        out[(size_t)N_ * D_ + N_ + 1] = (float)exp(red[0]);
    }
}

extern "C" void kernel_launch(void* const* d_in, const int* in_sizes, int n_in,
                              void* d_out, int out_size, void* d_ws, size_t ws_size,
                              hipStream_t stream) {
    const float* ze = (const float*)d_in[0];
    const float* cb = (const float*)d_in[1];
    float* out = (float*)d_out;
    float* ws  = (float*)d_ws;

    vq_init<<<dim3((K_ + 255) / 256), dim3(256), 0, stream>>>(cb, ws);
    vq_main<<<dim3(N_ / 64), dim3(256), 0, stream>>>(ze, cb, out, ws);
    vq_fix<<<dim3(64), dim3(256), 0, stream>>>(ze, cb, out, ws);
    vq_fin<<<dim3(1), dim3(K_), 0, stream>>>(ws, out);
}

// Round 11
// 189.525 us; speedup vs baseline: 1.0754x; 1.0754x over previous
//
#include <hip/hip_runtime.h>

// VectorQuantizerEMA: ze (32,64,2048) f32, codebook (1024,64) f32
#define B_   32
#define D_   64
#define TP_  2048
#define K_   1024
#define N_   (B_ * TP_)          // 65536 rows
#define BETA_ 0.25f

// ws layout (float units):
//   [0,1024)        : nc2[k] = np-replicated f32 ||c_k||^2 (pairwise-8 sum)
//   [1024]          : commit-loss accumulator (float, atomic)
//   [1025]          : ambiguous-row count (unsigned, atomic)
//   [1088,2112)     : histogram (unsigned, atomic)
//   [2112,18496)    : ambiguous list, u32 entries: (row<<10)|guess
//   [18496,84032)   : pre-swizzled bf16 split-table image, 32 tiles x 8KB.
//                     tile t = codes [t*32,t*32+32); per tile: 2048 ushorts hi,
//                     2048 lo; element (r=code&31, dim j) at ushort
//                     idx r*64 + (j ^ ((r&7)<<3))  [16B-chunk XOR swizzle]
#define WS_SC2   0
#define WS_LOSS  1024
#define WS_CNT   1025
#define WS_HIST  1088
#define WS_LIST  2112
#define WS_TBL   18496
#define CAP_     16384

#define MARGIN_  4e-4f

typedef __attribute__((ext_vector_type(8))) short short8v;   // 8 bf16
typedef __attribute__((ext_vector_type(4))) float float4v;   // C/D frag
#define AS1 __attribute__((address_space(1)))
#define AS3 __attribute__((address_space(3)))

static __device__ __forceinline__ unsigned bf16h(float f) {
    unsigned u = __float_as_uint(f);
    return (u + 0x7FFFu + ((u >> 16) & 1u)) >> 16;   // RNE to bf16
}

// ---------------- init: np ||c||^2, swizzled split tables, zero state --------
__global__ void vq_init(const float* __restrict__ cb, float* __restrict__ ws) {
    int k = blockIdx.x * blockDim.x + threadIdx.x;
    if (k < K_) {
        const float4* c4 = reinterpret_cast<const float4*>(cb + (size_t)k * D_);
        unsigned short* img  = reinterpret_cast<unsigned short*>(ws + WS_TBL);
        unsigned short* tile = img + (size_t)(k >> 5) * 4096;
        const int rr = k & 31;
        float r[8];
#pragma unroll
        for (int i = 0; i < 8; ++i) {
            float4 a = c4[2 * i], b = c4[2 * i + 1];
            float v[8] = {a.x, a.y, a.z, a.w, b.x, b.y, b.z, b.w};
            short8v hi, lo;
#pragma unroll
            for (int j = 0; j < 8; ++j) {
                unsigned hu = bf16h(v[j]);
                float hf = __uint_as_float(hu << 16);
                hi[j] = (short)hu;
                lo[j] = (short)bf16h(v[j] - hf);
                if (i == 0) r[j] = v[j] * v[j]; else r[j] += v[j] * v[j];
            }
            const int off = rr * 64 + ((8 * i) ^ ((rr & 7) << 3));
            *reinterpret_cast<short8v*>(&tile[off])        = hi;
            *reinterpret_cast<short8v*>(&tile[2048 + off]) = lo;
        }
        ws[WS_SC2 + k] = ((r[0] + r[1]) + (r[2] + r[3])) + ((r[4] + r[5]) + (r[6] + r[7]));
        reinterpret_cast<unsigned*>(ws + WS_HIST)[k] = 0u;
        if (k == 0) {
            ws[WS_LOSS] = 0.f;
            reinterpret_cast<unsigned*>(ws)[WS_CNT] = 0u;
        }
    }
}

// ---------------- main: 32 rows/wave MFMA GEMM + argmin + outputs ------------
// R10 post-mortem: per-step CU convoy {barrier, LDS reads, few MFMAs, argmin}
// left all pipes <30% busy; counted vmcnt was a no-op. Fix: double rows/wave
// (2 rowsets reuse every B fragment) -> 24 MFMA in 4 independent chains per
// step; MFMA issue (~930 cyc/SIMD/step) now exceeds LDS (~512) = busiest pipe.
// Grid 512 blocks (128 rows each): all work resident (2 blocks/CU).
__global__ __attribute__((amdgpu_flat_work_group_size(256, 256),
                          amdgpu_waves_per_eu(2, 2)))
void vq_main(const float* __restrict__ ze,
             const float* __restrict__ cb,
             float* __restrict__ out,
             float* __restrict__ ws) {
    __shared__ unsigned short lds[4][4096] __attribute__((aligned(16)));
    __shared__ float sc2_l[K_];
    __shared__ int bidx_sh[128];
    const int tid  = threadIdx.x;
    const int lane = tid & 63;
    const int w    = tid >> 6;
    const int kg   = lane >> 4;        // k-group 0..3
    const int rc   = lane & 15;        // A-row / B-col selector
    const int n0w  = blockIdx.x * 128 + w * 32;  // wave's first row

    // ---- A fragments, 2 rowsets: x[row = rs*16+rc][k=s*32+kg*8+e] ----
    short8v ah[2][2], al[2][2];
#pragma unroll
    for (int rs = 0; rs < 2; ++rs) {
        const int nA = n0w + rs * 16 + rc;
        const int bA = nA >> 11, tA = nA & (TP_ - 1);
        const float* zeA = ze + (size_t)bA * (D_ * TP_) + tA;
#pragma unroll
        for (int s = 0; s < 2; ++s) {
#pragma unroll
            for (int e = 0; e < 8; ++e) {
                float xv = zeA[(size_t)(s * 32 + kg * 8 + e) * TP_];
                unsigned hu = bf16h(xv);
                float hf = __uint_as_float(hu << 16);
                ah[rs][s][e] = (short)hu;
                al[rs][s][e] = (short)bf16h(xv - hf);
            }
        }
    }

    // stage sc2 (4KB) into LDS
    {
        const float* g = ws + WS_SC2 + w * 256 + lane * 4;
        __builtin_amdgcn_global_load_lds((const AS1 unsigned int*)g,
                                         (AS3 unsigned int*)&sc2_l[w * 256], 16, 0, 0);
    }
    const unsigned short* img = reinterpret_cast<const unsigned short*>(ws + WS_TBL);

    float best[2][4], best2[2][4];
    int   bidx[2][4];
#pragma unroll
    for (int rs = 0; rs < 2; ++rs)
#pragma unroll
        for (int r = 0; r < 4; ++r) {
            best[rs][r] = 3.4e38f; best2[rs][r] = 3.4e38f; bidx[rs][r] = 0;
        }

#define STAGE(tt) do {                                                            \
        const unsigned short* _g = img + (size_t)(tt) * 4096 + (size_t)tid * 8;   \
        unsigned short* _l = &lds[(tt) & 3][w * 512];                             \
        __builtin_amdgcn_global_load_lds((const AS1 unsigned int*)_g,             \
                                         (AS3 unsigned int*)_l, 16, 0, 0);        \
        __builtin_amdgcn_global_load_lds((const AS1 unsigned int*)(_g + 2048),    \
                                         (AS3 unsigned int*)(_l + 2048), 16, 0, 0); \
    } while (0)

#define SUBTILE(tt, sub) do {                                                     \
        const int r_  = (sub) * 16 + rc;                                          \
        const int cx0 = (kg * 8) ^ ((r_ & 7) << 3);                               \
        const int cx1 = (32 + kg * 8) ^ ((r_ & 7) << 3);                          \
        const unsigned short* bp = &lds[(tt) & 3][r_ * 64];                       \
        short8v bh0 = *reinterpret_cast<const short8v*>(bp + cx0);                \
        short8v bh1 = *reinterpret_cast<const short8v*>(bp + cx1);                \
        short8v bl0 = *reinterpret_cast<const short8v*>(bp + 2048 + cx0);         \
        short8v bl1 = *reinterpret_cast<const short8v*>(bp + 2048 + cx1);         \
        const int code = (tt) * 32 + (sub) * 16 + rc;                             \
        const float s2 = sc2_l[code];                                             \
        _Pragma("unroll")                                                         \
        for (int rs = 0; rs < 2; ++rs) {                                          \
            float4v acc = {0.f, 0.f, 0.f, 0.f};                                   \
            acc = __builtin_amdgcn_mfma_f32_16x16x32_bf16(ah[rs][0], bh0, acc, 0, 0, 0); \
            acc = __builtin_amdgcn_mfma_f32_16x16x32_bf16(ah[rs][1], bh1, acc, 0, 0, 0); \
            acc = __builtin_amdgcn_mfma_f32_16x16x32_bf16(ah[rs][0], bl0, acc, 0, 0, 0); \
            acc = __builtin_amdgcn_mfma_f32_16x16x32_bf16(ah[rs][1], bl1, acc, 0, 0, 0); \
            acc = __builtin_amdgcn_mfma_f32_16x16x32_bf16(al[rs][0], bh0, acc, 0, 0, 0); \
            acc = __builtin_amdgcn_mfma_f32_16x16x32_bf16(al[rs][1], bh1, acc, 0, 0, 0); \
            _Pragma("unroll")                                                     \
            for (int r = 0; r < 4; ++r) {                                         \
                float v = fmaf(-2.f, acc[r], s2);                                 \
                if (v < best[rs][r]) { best2[rs][r] = best[rs][r];                \
                    best[rs][r] = v; bidx[rs][r] = code; }                        \
                else if (v < best2[rs][r]) best2[rs][r] = v;                      \
            }                                                                     \
        }                                                                         \
    } while (0)

    __syncthreads();                  // drain A-loads + sc2 stage; publish sc2_l

    STAGE(0); STAGE(1); STAGE(2);     // depth-3 prologue (6 outstanding)
    for (int tt = 0; tt < 30; ++tt) {
        asm volatile("s_waitcnt vmcnt(4)" ::: "memory");   // tile tt retired
        __builtin_amdgcn_sched_barrier(0);
        __builtin_amdgcn_s_barrier();
        if (tt < 29) STAGE(tt + 3);
        SUBTILE(tt, 0);
        SUBTILE(tt, 1);
    }
    asm volatile("s_waitcnt vmcnt(2)" ::: "memory");
    __builtin_amdgcn_sched_barrier(0);
    __builtin_amdgcn_s_barrier();
    SUBTILE(30, 0); SUBTILE(30, 1);
    asm volatile("s_waitcnt vmcnt(0)" ::: "memory");
    __builtin_amdgcn_sched_barrier(0);
    __builtin_amdgcn_s_barrier();
    SUBTILE(31, 0); SUBTILE(31, 1);
#undef STAGE
#undef SUBTILE

    // reduce (best,best2,idx) across the 16 cols (low 4 lane bits)
#pragma unroll
    for (int rs = 0; rs < 2; ++rs)
#pragma unroll
    for (int r = 0; r < 4; ++r) {
        unsigned fu = __float_as_uint(best[rs][r]);
        fu = (fu & 0x80000000u) ? ~fu : (fu | 0x80000000u);   // order-preserving
        unsigned long long pk = ((unsigned long long)fu << 32) | (unsigned)bidx[rs][r];
        float bf = best[rs][r], b2 = best2[rs][r];
#pragma unroll
        for (int m = 1; m <= 8; m <<= 1) {
            unsigned long long po = __shfl_xor(pk, m, 64);
            float bo  = __shfl_xor(bf, m, 64);
            float b2o = __shfl_xor(b2, m, 64);
            b2 = fminf(fminf(b2, b2o), fmaxf(bf, bo));
            bf = fminf(bf, bo);
            if (po < pk) pk = po;
        }
        best[rs][r] = bf; best2[rs][r] = b2; bidx[rs][r] = (int)(pk & 0x3FFull);
    }

    if (rc == 0) {
        unsigned* gh = reinterpret_cast<unsigned*>(ws + WS_HIST);
#pragma unroll
        for (int rs = 0; rs < 2; ++rs)
#pragma unroll
        for (int r = 0; r < 4; ++r) {
            const int row = rs * 16 + kg * 4 + r;    // row within wave tile
            const int n   = n0w + row;
            const int k   = bidx[rs][r];
            out[(size_t)N_ * D_ + n] = (float)k;
            atomicAdd(&gh[k], 1u);
            if (best2[rs][r] - best[rs][r] < MARGIN_) {
                unsigned slot = atomicAdd(reinterpret_cast<unsigned*>(ws) + WS_CNT, 1u);
                if (slot < CAP_)
                    reinterpret_cast<unsigned*>(ws + WS_LIST)[slot] =
                        ((unsigned)n << 10) | (unsigned)k;
            }
            bidx_sh[w * 32 + row] = k;
        }
    }
    __syncthreads();

    // ---- phase2: zq gather-write + commit loss (128 rows, 2 dim-chunks) ----
    const int row   = tid & 127;
    const int chunk = tid >> 7;                    // dims [chunk*32, +32)
    const int n2 = blockIdx.x * 128 + row;
    const int b2i = n2 >> 11, t2 = n2 & (TP_ - 1);
    const int k2 = bidx_sh[row];
    const float* zer = ze + (size_t)b2i * (D_ * TP_) + t2;
    float* outr = out + (size_t)b2i * (D_ * TP_) + t2;
    const float4* cr4 = reinterpret_cast<const float4*>(cb + (size_t)k2 * D_ + chunk * 32);
    float lsum = 0.f;
#pragma unroll
    for (int q4 = 0; q4 < 8; ++q4) {
        float4 q = cr4[q4];
        float qv[4] = {q.x, q.y, q.z, q.w};
#pragma unroll
        for (int c = 0; c < 4; ++c) {
            const int d = chunk * 32 + q4 * 4 + c;
            outr[(size_t)d * TP_] = qv[c];        // ze + (zq - ze) == zq
            float diff = zer[(size_t)d * TP_] - qv[c];
            lsum = fmaf(diff, diff, lsum);
        }
    }
#pragma unroll
    for (int m = 32; m >= 1; m >>= 1) lsum += __shfl_xor(lsum, m, 64);
    if (lane == 0) atomicAdd(ws + WS_LOSS, lsum);
}

// ---------------- fixup: replicate ref grid argmin for ambiguous rows -------
// Row x lives in LDS read via volatile pointer (spill-immune, ~40 VGPR).
__global__ __attribute__((amdgpu_flat_work_group_size(256, 256)))
void vq_fix(const float* __restrict__ ze,
            const float* __restrict__ cb,
            float* __restrict__ out,
            float* __restrict__ ws) {
    __shared__ float xls[4][64];
    const int lane = threadIdx.x & 63;
    const int wl   = threadIdx.x >> 6;
    const unsigned w = blockIdx.x * 4 + wl;                  // wave id, 256 total
    unsigned cnt = reinterpret_cast<const unsigned*>(ws)[WS_CNT];
    if (cnt > CAP_) cnt = CAP_;
    const unsigned* list = reinterpret_cast<const unsigned*>(ws + WS_LIST);
    const float* sc2 = ws + WS_SC2;
    unsigned* gh = reinterpret_cast<unsigned*>(ws + WS_HIST);

    for (unsigned i = w; i < cnt; i += 256) {
        unsigned e = list[i];
        const int n     = (int)(e >> 10);
        const int guess = (int)(e & 1023u);
        const int b  = n >> 11;
        const int tp = n & (TP_ - 1);
        const float* zp = ze + (size_t)b * D_ * TP_ + tp;    // wave-uniform

        xls[wl][lane] = zp[(size_t)lane * TP_];
        asm volatile("s_waitcnt lgkmcnt(0)" ::: "memory");

        volatile const float* xw = xls[wl];

        float r[8];
#pragma unroll
        for (int j = 0; j < 8; ++j) { float v = xw[j]; r[j] = v * v; }
#pragma unroll
        for (int ii = 1; ii < 8; ++ii)
#pragma unroll
            for (int j = 0; j < 8; ++j) { float v = xw[8 * ii + j]; r[j] += v * v; }
        float nx2 = ((r[0] + r[1]) + (r[2] + r[3])) + ((r[4] + r[5]) + (r[6] + r[7]));

        unsigned long long m = ~0ull;
        const int kbase = lane * 16;
#pragma unroll 1
        for (int kk = 0; kk < 16; ++kk) {
            const int k = kbase + kk;
            const float* cp = cb + (size_t)k * D_;
            double acc = 0.0;
#pragma unroll
            for (int j = 0; j < D_; ++j)
                acc = fma((double)xw[j], (double)cp[j], acc);
            float dotf = (float)acc;
            float A    = nx2 + sc2[k];
            float dist = A - 2.0f * dotf;
            unsigned long long pk =
                ((unsigned long long)__float_as_uint(dist) << 32) | (unsigned)k;
            if (pk < m) m = pk;
        }
#pragma unroll
        for (int s = 32; s >= 1; s >>= 1) {
            unsigned long long o = __shfl_xor(m, s, 64);
            if (o < m) m = o;
        }
        const int gk = (int)(m & 0xFFFFFFFFull);

        if (gk != guess) {
            out[(size_t)b * D_ * TP_ + (size_t)lane * TP_ + tp] = cb[(size_t)gk * D_ + lane];
            float xl = xw[lane];
            float dn = xl - cb[(size_t)gk * D_ + lane];
            float dq = xl - cb[(size_t)guess * D_ + lane];
            float t  = dn * dn - dq * dq;
#pragma unroll
            for (int s = 32; s >= 1; s >>= 1) t += __shfl_xor(t, s, 64);
            if (lane == 0) {
                atomicAdd(ws + WS_LOSS, t);
                out[(size_t)N_ * D_ + n] = (float)gk;
                atomicSub(&gh[guess], 1u);
                atomicAdd(&gh[gk], 1u);
            }
        }
    }
}

// ---------------- finalize: scalars ----------------
__global__ void vq_fin(const float* __restrict__ ws, float* __restrict__ out) {
    __shared__ double red[K_];
    const int t = threadIdx.x;
    const unsigned* gh = reinterpret_cast<const unsigned*>(ws + WS_HIST);
    double p = (double)gh[t] * (1.0 / (double)N_);
    red[t] = -p * log(p + 1e-10);
    __syncthreads();
    for (int s = 512; s > 0; s >>= 1) {
        if (t < s) red[t] += red[t + s];
        __syncthreads();
    }
    if (t == 0) {
        out[(size_t)N_ * D_ + N_]     = BETA_ * ws[WS_LOSS] * (1.0f / (float)(N_ * D_));
        out[(size_t)N_ * D_ + N_ + 1] = (float)exp(red[0]);
    }
}

extern "C" void kernel_launch(void* const* d_in, const int* in_sizes, int n_in,
                              void* d_out, int out_size, void* d_ws, size_t ws_size,
                              hipStream_t stream) {
    const float* ze = (const float*)d_in[0];
    const float* cb = (const float*)d_in[1];
    float* out = (float*)d_out;
    float* ws  = (float*)d_ws;

    vq_init<<<dim3(16), dim3(64), 0, stream>>>(cb, ws);
    vq_main<<<dim3(N_ / 128), dim3(256), 0, stream>>>(ze, cb, out, ws);
    vq_fix<<<dim3(64), dim3(256), 0, stream>>>(ze, cb, out, ws);
    vq_fin<<<dim3(1), dim3(K_), 0, stream>>>(ws, out);
}

// Round 12
// 154.888 us; speedup vs baseline: 1.3159x; 1.2236x over previous
//
#include <hip/hip_runtime.h>

// VectorQuantizerEMA: ze (32,64,2048) f32, codebook (1024,64) f32
#define B_   32
#define D_   64
#define TP_  2048
#define K_   1024
#define N_   (B_ * TP_)          // 65536 rows
#define BETA_ 0.25f

// ws layout (float units):
//   [0,1024)        : nc2[k] = np-replicated f32 ||c_k||^2 (pairwise-8 sum)
//   [1024]          : commit-loss accumulator (float, atomic)
//   [1025]          : ambiguous-row count (unsigned, atomic)
//   [1088,2112)     : histogram (unsigned, atomic)
//   [2112,18496)    : ambiguous list, u32 entries: (row<<10)|guess
//   [18496,84032)   : pre-swizzled bf16 split-table image, 16 tiles x 16KB.
//                     tile t = codes [t*64, t*64+64); per tile: 4096 ushorts hi,
//                     4096 lo; element (r=code&63, dim j) at ushort
//                     idx r*64 + (j ^ ((r&7)<<3))  [16B-chunk XOR swizzle]
#define WS_SC2   0
#define WS_LOSS  1024
#define WS_CNT   1025
#define WS_HIST  1088
#define WS_LIST  2112
#define WS_TBL   18496
#define CAP_     16384

#define MARGIN_  4e-4f

typedef __attribute__((ext_vector_type(8))) short short8v;   // 8 bf16
typedef __attribute__((ext_vector_type(4))) float float4v;   // C/D frag
#define AS1 __attribute__((address_space(1)))
#define AS3 __attribute__((address_space(3)))

static __device__ __forceinline__ unsigned bf16h(float f) {
    unsigned u = __float_as_uint(f);
    return (u + 0x7FFFu + ((u >> 16) & 1u)) >> 16;   // RNE to bf16
}

// ---------------- init: np ||c||^2, swizzled split tables, zero state --------
__global__ void vq_init(const float* __restrict__ cb, float* __restrict__ ws) {
    int k = blockIdx.x * blockDim.x + threadIdx.x;
    if (k < K_) {
        const float4* c4 = reinterpret_cast<const float4*>(cb + (size_t)k * D_);
        unsigned short* img  = reinterpret_cast<unsigned short*>(ws + WS_TBL);
        unsigned short* tile = img + (size_t)(k >> 6) * 8192;
        const int rr = k & 63;
        float r[8];
#pragma unroll
        for (int i = 0; i < 8; ++i) {
            float4 a = c4[2 * i], b = c4[2 * i + 1];
            float v[8] = {a.x, a.y, a.z, a.w, b.x, b.y, b.z, b.w};
            short8v hi, lo;
#pragma unroll
            for (int j = 0; j < 8; ++j) {
                unsigned hu = bf16h(v[j]);
                float hf = __uint_as_float(hu << 16);
                hi[j] = (short)hu;
                lo[j] = (short)bf16h(v[j] - hf);
                if (i == 0) r[j] = v[j] * v[j]; else r[j] += v[j] * v[j];
            }
            const int off = rr * 64 + ((8 * i) ^ ((rr & 7) << 3));
            *reinterpret_cast<short8v*>(&tile[off])        = hi;
            *reinterpret_cast<short8v*>(&tile[4096 + off]) = lo;
        }
        ws[WS_SC2 + k] = ((r[0] + r[1]) + (r[2] + r[3])) + ((r[4] + r[5]) + (r[6] + r[7]));
        reinterpret_cast<unsigned*>(ws + WS_HIST)[k] = 0u;
        if (k == 0) {
            ws[WS_LOSS] = 0.f;
            reinterpret_cast<unsigned*>(ws)[WS_CNT] = 0u;
        }
    }
}

// ---------------- main: 64-code tiles, 16-step 2-phase MFMA GEMM -------------
// R9-R11 invariant ~95-105us across schedule variants at 32 steps => per-step
// fixed cost dominates. Halve step count: 64-code tiles (16KB), 2 buffers,
// catalog-minimum 2-phase: vmcnt(0) at top (stage issued a FULL step earlier
// -> drain is free), barrier, STAGE(tt+1), 4 subtiles.
__global__ __attribute__((amdgpu_flat_work_group_size(256, 256),
                          amdgpu_waves_per_eu(2, 2)))
void vq_main(const float* __restrict__ ze,
             const float* __restrict__ cb,
             float* __restrict__ out,
             float* __restrict__ ws) {
    __shared__ unsigned short lds[2][8192] __attribute__((aligned(16)));
    __shared__ float sc2_l[K_];
    __shared__ int bidx_sh[128];
    const int tid  = threadIdx.x;
    const int lane = tid & 63;
    const int w    = tid >> 6;
    const int kg   = lane >> 4;        // k-group 0..3
    const int rc   = lane & 15;        // A-row / B-col selector
    const int n0w  = blockIdx.x * 128 + w * 32;  // wave's first row

    // ---- A fragments, 2 rowsets: x[row = rs*16+rc][k=s*32+kg*8+e] ----
    short8v ah[2][2], al[2][2];
#pragma unroll
    for (int rs = 0; rs < 2; ++rs) {
        const int nA = n0w + rs * 16 + rc;
        const int bA = nA >> 11, tA = nA & (TP_ - 1);
        const float* zeA = ze + (size_t)bA * (D_ * TP_) + tA;
#pragma unroll
        for (int s = 0; s < 2; ++s) {
#pragma unroll
            for (int e = 0; e < 8; ++e) {
                float xv = zeA[(size_t)(s * 32 + kg * 8 + e) * TP_];
                unsigned hu = bf16h(xv);
                float hf = __uint_as_float(hu << 16);
                ah[rs][s][e] = (short)hu;
                al[rs][s][e] = (short)bf16h(xv - hf);
            }
        }
    }

    // stage sc2 (4KB) into LDS
    {
        const float* g = ws + WS_SC2 + w * 256 + lane * 4;
        __builtin_amdgcn_global_load_lds((const AS1 unsigned int*)g,
                                         (AS3 unsigned int*)&sc2_l[w * 256], 16, 0, 0);
    }
    const unsigned short* img = reinterpret_cast<const unsigned short*>(ws + WS_TBL);

    float best[2][4], best2[2][4];
    int   bidx[2][4];
#pragma unroll
    for (int rs = 0; rs < 2; ++rs)
#pragma unroll
        for (int r = 0; r < 4; ++r) {
            best[rs][r] = 3.4e38f; best2[rs][r] = 3.4e38f; bidx[rs][r] = 0;
        }

    // stage tile tt (16KB): 4 x 16B per thread, linear dest
#define STAGE(tt) do {                                                            \
        const unsigned short* _g = img + (size_t)(tt) * 8192;                     \
        unsigned short* _l = lds[(tt) & 1];                                       \
        _Pragma("unroll")                                                         \
        for (int _c = 0; _c < 4; ++_c) {                                          \
            __builtin_amdgcn_global_load_lds(                                     \
                (const AS1 unsigned int*)(_g + _c * 2048 + (size_t)tid * 8),      \
                (AS3 unsigned int*)(_l + _c * 2048 + w * 512), 16, 0, 0);         \
        }                                                                         \
    } while (0)

#define SUBTILE(tt, sub) do {                                                     \
        const int r_  = (sub) * 16 + rc;                                          \
        const int cx0 = (kg * 8) ^ ((r_ & 7) << 3);                               \
        const int cx1 = (32 + kg * 8) ^ ((r_ & 7) << 3);                          \
        const unsigned short* bp = &lds[(tt) & 1][r_ * 64];                       \
        short8v bh0 = *reinterpret_cast<const short8v*>(bp + cx0);                \
        short8v bh1 = *reinterpret_cast<const short8v*>(bp + cx1);                \
        short8v bl0 = *reinterpret_cast<const short8v*>(bp + 4096 + cx0);         \
        short8v bl1 = *reinterpret_cast<const short8v*>(bp + 4096 + cx1);         \
        const int code = (tt) * 64 + (sub) * 16 + rc;                             \
        const float s2 = sc2_l[code];                                             \
        _Pragma("unroll")                                                         \
        for (int rs = 0; rs < 2; ++rs) {                                          \
            float4v acc = {0.f, 0.f, 0.f, 0.f};                                   \
            acc = __builtin_amdgcn_mfma_f32_16x16x32_bf16(ah[rs][0], bh0, acc, 0, 0, 0); \
            acc = __builtin_amdgcn_mfma_f32_16x16x32_bf16(ah[rs][1], bh1, acc, 0, 0, 0); \
            acc = __builtin_amdgcn_mfma_f32_16x16x32_bf16(ah[rs][0], bl0, acc, 0, 0, 0); \
            acc = __builtin_amdgcn_mfma_f32_16x16x32_bf16(ah[rs][1], bl1, acc, 0, 0, 0); \
            acc = __builtin_amdgcn_mfma_f32_16x16x32_bf16(al[rs][0], bh0, acc, 0, 0, 0); \
            acc = __builtin_amdgcn_mfma_f32_16x16x32_bf16(al[rs][1], bh1, acc, 0, 0, 0); \
            _Pragma("unroll")                                                     \
            for (int r = 0; r < 4; ++r) {                                         \
                float v = fmaf(-2.f, acc[r], s2);                                 \
                if (v < best[rs][r]) { best2[rs][r] = best[rs][r];                \
                    best[rs][r] = v; bidx[rs][r] = code; }                        \
                else if (v < best2[rs][r]) best2[rs][r] = v;                      \
            }                                                                     \
        }                                                                         \
    } while (0)

    STAGE(0);                          // + A-loads + sc2 stage outstanding
    for (int tt = 0; tt < 16; ++tt) {
        asm volatile("s_waitcnt vmcnt(0)" ::: "memory");  // stage tt done (free: issued 1 step ago)
        __builtin_amdgcn_sched_barrier(0);
        __builtin_amdgcn_s_barrier();                     // all waves done reading buf tt^1
        if (tt < 15) STAGE(tt + 1);                       // prefetch into buf tt^1
        __builtin_amdgcn_sched_barrier(0);                // pin issue before compute
        SUBTILE(tt, 0);
        SUBTILE(tt, 1);
        SUBTILE(tt, 2);
        SUBTILE(tt, 3);
    }
#undef STAGE
#undef SUBTILE

    // reduce (best,best2,idx) across the 16 cols (low 4 lane bits)
#pragma unroll
    for (int rs = 0; rs < 2; ++rs)
#pragma unroll
    for (int r = 0; r < 4; ++r) {
        unsigned fu = __float_as_uint(best[rs][r]);
        fu = (fu & 0x80000000u) ? ~fu : (fu | 0x80000000u);   // order-preserving
        unsigned long long pk = ((unsigned long long)fu << 32) | (unsigned)bidx[rs][r];
        float bf = best[rs][r], b2 = best2[rs][r];
#pragma unroll
        for (int m = 1; m <= 8; m <<= 1) {
            unsigned long long po = __shfl_xor(pk, m, 64);
            float bo  = __shfl_xor(bf, m, 64);
            float b2o = __shfl_xor(b2, m, 64);
            b2 = fminf(fminf(b2, b2o), fmaxf(bf, bo));
            bf = fminf(bf, bo);
            if (po < pk) pk = po;
        }
        best[rs][r] = bf; best2[rs][r] = b2; bidx[rs][r] = (int)(pk & 0x3FFull);
    }

    if (rc == 0) {
        unsigned* gh = reinterpret_cast<unsigned*>(ws + WS_HIST);
#pragma unroll
        for (int rs = 0; rs < 2; ++rs)
#pragma unroll
        for (int r = 0; r < 4; ++r) {
            const int row = rs * 16 + kg * 4 + r;    // row within wave tile
            const int n   = n0w + row;
            const int k   = bidx[rs][r];
            out[(size_t)N_ * D_ + n] = (float)k;
            atomicAdd(&gh[k], 1u);
            if (best2[rs][r] - best[rs][r] < MARGIN_) {
                unsigned slot = atomicAdd(reinterpret_cast<unsigned*>(ws) + WS_CNT, 1u);
                if (slot < CAP_)
                    reinterpret_cast<unsigned*>(ws + WS_LIST)[slot] =
                        ((unsigned)n << 10) | (unsigned)k;
            }
            bidx_sh[w * 32 + row] = k;
        }
    }
    __syncthreads();

    // ---- phase2: zq gather-write + commit loss (128 rows, 2 dim-chunks) ----
    const int row   = tid & 127;
    const int chunk = tid >> 7;                    // dims [chunk*32, +32)
    const int n2 = blockIdx.x * 128 + row;
    const int b2i = n2 >> 11, t2 = n2 & (TP_ - 1);
    const int k2 = bidx_sh[row];
    const float* zer = ze + (size_t)b2i * (D_ * TP_) + t2;
    float* outr = out + (size_t)b2i * (D_ * TP_) + t2;
    const float4* cr4 = reinterpret_cast<const float4*>(cb + (size_t)k2 * D_ + chunk * 32);
    float lsum = 0.f;
#pragma unroll
    for (int q4 = 0; q4 < 8; ++q4) {
        float4 q = cr4[q4];
        float qv[4] = {q.x, q.y, q.z, q.w};
#pragma unroll
        for (int c = 0; c < 4; ++c) {
            const int d = chunk * 32 + q4 * 4 + c;
            outr[(size_t)d * TP_] = qv[c];        // ze + (zq - ze) == zq
            float diff = zer[(size_t)d * TP_] - qv[c];
            lsum = fmaf(diff, diff, lsum);
        }
    }
#pragma unroll
    for (int m = 32; m >= 1; m >>= 1) lsum += __shfl_xor(lsum, m, 64);
    if (lane == 0) atomicAdd(ws + WS_LOSS, lsum);
}

// ---------------- fixup: replicate ref grid argmin for ambiguous rows -------
// R11: volatile scalar LDS reads serialized 1024 dependent ds_read_b32/row
// (~75us). Now: x in LDS read as float4 (ds_read_b128, pipelined), 4-way f64
// accumulators; per-code asm memory clobber defeats LICM hoisting (the spill
// source). Live regs ~30 by construction.
__global__ __attribute__((amdgpu_flat_work_group_size(256, 256)))
void vq_fix(const float* __restrict__ ze,
            const float* __restrict__ cb,
            float* __restrict__ out,
            float* __restrict__ ws) {
    __shared__ float xls[4][64];
    const int lane = threadIdx.x & 63;
    const int wl   = threadIdx.x >> 6;
    const unsigned w = blockIdx.x * 4 + wl;                  // wave id, 256 total
    unsigned cnt = reinterpret_cast<const unsigned*>(ws)[WS_CNT];
    if (cnt > CAP_) cnt = CAP_;
    const unsigned* list = reinterpret_cast<const unsigned*>(ws + WS_LIST);
    const float* sc2 = ws + WS_SC2;
    unsigned* gh = reinterpret_cast<unsigned*>(ws + WS_HIST);

    for (unsigned i = w; i < cnt; i += 256) {
        unsigned e = list[i];
        const int n     = (int)(e >> 10);
        const int guess = (int)(e & 1023u);
        const int b  = n >> 11;
        const int tp = n & (TP_ - 1);
        const float* zp = ze + (size_t)b * D_ * TP_ + tp;    // wave-uniform

        xls[wl][lane] = zp[(size_t)lane * TP_];
        asm volatile("s_waitcnt lgkmcnt(0)" ::: "memory");

        // np pairwise-8 ||x||^2 (bit-exact np.sum(x*x, axis=1))
        float r[8];
#pragma unroll
        for (int j = 0; j < 8; ++j) { float v = xls[wl][j]; r[j] = v * v; }
#pragma unroll
        for (int ii = 1; ii < 8; ++ii)
#pragma unroll
            for (int j = 0; j < 8; ++j) { float v = xls[wl][8 * ii + j]; r[j] += v * v; }
        float nx2 = ((r[0] + r[1]) + (r[2] + r[3])) + ((r[4] + r[5]) + (r[6] + r[7]));

        const float4* x4 = reinterpret_cast<const float4*>(xls[wl]);
        unsigned long long m = ~0ull;
        const int kbase = lane * 16;
#pragma unroll 1
        for (int kk = 0; kk < 16; ++kk) {
            const int k = kbase + kk;
            const float4* cp4 = reinterpret_cast<const float4*>(cb + (size_t)k * D_);
            asm volatile("" ::: "memory");       // force x4 re-reads (no 64-reg hoist)
            double a0 = 0.0, a1 = 0.0, a2 = 0.0, a3 = 0.0;
#pragma unroll
            for (int j4 = 0; j4 < 16; ++j4) {
                float4 xv = x4[j4];
                float4 cv = cp4[j4];
                a0 = fma((double)xv.x, (double)cv.x, a0);
                a1 = fma((double)xv.y, (double)cv.y, a1);
                a2 = fma((double)xv.z, (double)cv.z, a2);
                a3 = fma((double)xv.w, (double)cv.w, a3);
            }
            float dotf = (float)((a0 + a1) + (a2 + a3));
            float A    = nx2 + sc2[k];
            float dist = A - 2.0f * dotf;
            unsigned long long pk =
                ((unsigned long long)__float_as_uint(dist) << 32) | (unsigned)k;
            if (pk < m) m = pk;
        }
#pragma unroll
        for (int s = 32; s >= 1; s >>= 1) {
            unsigned long long o = __shfl_xor(m, s, 64);
            if (o < m) m = o;
        }
        const int gk = (int)(m & 0xFFFFFFFFull);

        if (gk != guess) {
            out[(size_t)b * D_ * TP_ + (size_t)lane * TP_ + tp] = cb[(size_t)gk * D_ + lane];
            float xl = xls[wl][lane];
            float dn = xl - cb[(size_t)gk * D_ + lane];
            float dq = xl - cb[(size_t)guess * D_ + lane];
            float t  = dn * dn - dq * dq;
#pragma unroll
            for (int s = 32; s >= 1; s >>= 1) t += __shfl_xor(t, s, 64);
            if (lane == 0) {
                atomicAdd(ws + WS_LOSS, t);
                out[(size_t)N_ * D_ + n] = (float)gk;
                atomicSub(&gh[guess], 1u);
                atomicAdd(&gh[gk], 1u);
            }
        }
    }
}

// ---------------- finalize: scalars ----------------
__global__ void vq_fin(const float* __restrict__ ws, float* __restrict__ out) {
    __shared__ double red[K_];
    const int t = threadIdx.x;
    const unsigned* gh = reinterpret_cast<const unsigned*>(ws + WS_HIST);
    double p = (double)gh[t] * (1.0 / (double)N_);
    red[t] = -p * log(p + 1e-10);
    __syncthreads();
    for (int s = 512; s > 0; s >>= 1) {
        if (t < s) red[t] += red[t + s];
        __syncthreads();
    }
    if (t == 0) {
        out[(size_t)N_ * D_ + N_]     = BETA_ * ws[WS_LOSS] * (1.0f / (float)(N_ * D_));
        out[(size_t)N_ * D_ + N_ + 1] = (float)exp(red[0]);
    }
}

extern "C" void kernel_launch(void* const* d_in, const int* in_sizes, int n_in,
                              void* d_out, int out_size, void* d_ws, size_t ws_size,
                              hipStream_t stream) {
    const float* ze = (const float*)d_in[0];
    const float* cb = (const float*)d_in[1];
    float* out = (float*)d_out;
    float* ws  = (float*)d_ws;

    vq_init<<<dim3(16), dim3(64), 0, stream>>>(cb, ws);
    vq_main<<<dim3(N_ / 128), dim3(256), 0, stream>>>(ze, cb, out, ws);
    vq_fix<<<dim3(64), dim3(256), 0, stream>>>(ze, cb, out, ws);
    vq_fin<<<dim3(1), dim3(K_), 0, stream>>>(ws, out);
}